// Round 8
// baseline (46.306 us; speedup 1.0000x reference)
//
#include <hip/hip_runtime.h>

// StructOnlyClassifier R8: perfect-stream decomposition.
//  K1 sample_bounds: batch[256i] samples; windows containing boundaries are
//     streamed once (window is sorted) with a merge pass writing exact
//     S[g]=lower_bound(batch,g). Also gof[w]=batch[1024w]. Chain depth ~2.
//  K2 stream: wave w owns FIXED nodes [1024w,1024w+1024): 16 dwordx4/lane,
//     perfectly coalesced (copy-benchmark address pattern). Per-quad packed
//     type-counts; interval select via L2-hot S; wave reduce; ~2 u64
//     atomics/graph into hist.
//  K3 mlp: per-graph 4->32->16->1 MLP from packed hist (R1's proven kernel).

constexpr int SSTR = 256;   // sample stride (nodes)

__global__ __launch_bounds__(256) void sample_bounds_kernel(
    const int* __restrict__ batch, int* __restrict__ S, int* __restrict__ gof,
    int n, int B)
{
    const int i = blockIdx.x * 256 + threadIdx.x;
    const int nsamp = n / SSTR;
    if (i >= nsamp) return;
    const int base = i * SSTR;
    const int v = batch[base];
    if ((i & 3) == 0) gof[i >> 2] = v;                 // graph id of node 1024*(i/4)
    const int vnext = (i + 1 < nsamp) ? batch[base + SSTR] : B;
    if (i == 0) {
        for (int g = 0; g <= v; ++g) S[g] = 0;         // all elems >= batch[0]
    }
    if (vnext > v) {
        // boundaries S[g] for g in (v, vnext] lie in (base, base+256]
        int gcur = v + 1;
        const int4* b4 = (const int4*)(batch + base);
        for (int ch = 0; ch < 8; ++ch) {               // 8 chunks x 8 int4 = 256 ints
            int4 q[8];
            #pragma unroll
            for (int u = 0; u < 8; ++u) q[u] = b4[ch * 8 + u];
            #pragma unroll
            for (int u = 0; u < 8; ++u) {
                const int e[4] = {q[u].x, q[u].y, q[u].z, q[u].w};
                #pragma unroll
                for (int c = 0; c < 4; ++c) {
                    const int k = base + ch * 32 + u * 4 + c;
                    while (gcur <= vnext && e[c] >= gcur) { S[gcur] = k; ++gcur; }
                }
            }
        }
        while (gcur <= vnext) { S[gcur] = base + SSTR; ++gcur; }
    }
}

// packed u64 hist: [0:16)=cnt(t==0) [16:32)=cnt(t==1) [32:48)=cnt(t==2) [48:64)=total
__global__ __launch_bounds__(256) void stream_kernel(
    const int* __restrict__ ntype, const int* __restrict__ S,
    const int* __restrict__ gof, unsigned long long* __restrict__ hist, int n)
{
    const int tid  = threadIdx.x;
    const int w    = (blockIdx.x * 256 + tid) >> 6;    // one wave per 1024 nodes
    const int lane = tid & 63;
    const int ws   = w * 1024;
    if (ws >= n) return;
    const int we = min(ws + 1024, n);

    const int4* nt4 = (const int4*)ntype;
    const int nqm1 = (n >> 2) - 1;
    int4 t[4];
    const int q0 = (ws >> 2) + lane;
    #pragma unroll
    for (int u = 0; u < 4; ++u) t[u] = nt4[min(q0 + u * 64, nqm1)]; // 4 indep 16B loads

    unsigned long long qp[4];                          // packed counts per quad
    #pragma unroll
    for (int u = 0; u < 4; ++u) {
        const int x = t[u].x, y = t[u].y, z = t[u].z, ww = t[u].w;
        const unsigned c0 = (x == 0) + (y == 0) + (z == 0) + (ww == 0);
        const unsigned c1 = (x == 1) + (y == 1) + (z == 1) + (ww == 1);
        const unsigned c2 = (x == 2) + (y == 2) + (z == 2) + (ww == 2);
        qp[u] = (unsigned long long)c0 | ((unsigned long long)c1 << 16)
              | ((unsigned long long)c2 << 32) | (4ull << 48);
    }

    int gcur = gof[w];                                 // graph containing node ws
    int lo = ws;
    for (;;) {
        const int b  = S[gcur + 1];                    // L2-hot (S is 64 KiB)
        const int hi = min(b, we);
        unsigned long long acc = 0;
        #pragma unroll
        for (int u = 0; u < 4; ++u) {
            const int qb = ws + u * 256 + lane * 4;
            if (qb >= lo && qb + 4 <= hi) {
                acc += qp[u];                          // quad fully inside interval
            } else if (qb < hi && qb + 4 > lo) {       // straddling quad (rare)
                const int e[4] = {t[u].x, t[u].y, t[u].z, t[u].w};
                #pragma unroll
                for (int c = 0; c < 4; ++c) {
                    const int idx = qb + c;
                    if (idx >= lo && idx < hi)
                        acc += (1ull << (e[c] * 16)) | (1ull << 48);
                }
            }
        }
        #pragma unroll
        for (int off = 32; off; off >>= 1) acc += __shfl_xor(acc, off);
        if (lane == 0 && acc) atomicAdd(&hist[gcur], acc);
        if (b >= we) break;
        ++gcur; lo = b;
    }
}

__global__ __launch_bounds__(256) void mlp_kernel(
    const unsigned long long* __restrict__ hist,
    const float* __restrict__ W1, const float* __restrict__ b1,
    const float* __restrict__ W2, const float* __restrict__ b2,
    const float* __restrict__ W3, const float* __restrict__ b3,
    float* __restrict__ out, int B)
{
    __shared__ float sW1[128], sb1[32], sW2[512], sb2[16], sW3[16], sb3[1];
    const int tid = threadIdx.x;
    for (int i = tid; i < 128; i += 256) sW1[i] = W1[i];
    for (int i = tid; i < 512; i += 256) sW2[i] = W2[i];
    if (tid < 32)  sb1[tid] = b1[tid];
    if (tid < 16)  sb2[tid] = b2[tid];
    if (tid >= 32 && tid < 48) sW3[tid - 32] = W3[tid - 32];
    if (tid == 0)  sb3[0] = b3[0];
    __syncthreads();

    const int g = blockIdx.x * blockDim.x + tid;
    if (g >= B) return;

    const unsigned long long h = hist[g];
    const float f0 = (float)(int)( h        & 0xFFFFull) - 54.5f;
    const float f1 = (float)(int)((h >> 16) & 0xFFFFull);
    const float f2 = (float)(int)((h >> 32) & 0xFFFFull);
    const float f3 = (float)(int)( h >> 48)              - 56.5f;

    float h1[32];
    #pragma unroll
    for (int j = 0; j < 32; ++j) {
        float s = sb1[j];
        s = fmaf(f0, sW1[      j], s);
        s = fmaf(f1, sW1[ 32 + j], s);
        s = fmaf(f2, sW1[ 64 + j], s);
        s = fmaf(f3, sW1[ 96 + j], s);
        h1[j] = fmaxf(0.0f, s);
    }
    float h2[16];
    #pragma unroll
    for (int m = 0; m < 16; ++m) {
        float s = sb2[m];
        #pragma unroll
        for (int j = 0; j < 32; ++j)
            s = fmaf(h1[j], sW2[j * 16 + m], s);
        h2[m] = fmaxf(0.0f, s);
    }
    float o = sb3[0];
    #pragma unroll
    for (int m = 0; m < 16; ++m)
        o = fmaf(h2[m], sW3[m], o);
    out[g] = o;
}

extern "C" void kernel_launch(void* const* d_in, const int* in_sizes, int n_in,
                              void* d_out, int out_size, void* d_ws, size_t ws_size,
                              hipStream_t stream) {
    // inputs: 0:x(N) 1:batch(N) 2:node_type(N) 3:num_graphs 4:W1 5:b1 6:W2 7:b2 8:W3 9:b3
    const int*   batch = (const int*)d_in[1];
    const int*   ntype = (const int*)d_in[2];
    const float* W1    = (const float*)d_in[4];
    const float* b1    = (const float*)d_in[5];
    const float* W2    = (const float*)d_in[6];
    const float* b2    = (const float*)d_in[7];
    const float* W3    = (const float*)d_in[8];
    const float* b3    = (const float*)d_in[9];
    float*       out   = (float*)d_out;

    const int n = in_sizes[1];          // 16,777,216 nodes
    const int B = out_size;             // 16,384 graphs

    // workspace layout: S[B+1] @0 (65,540 B) | gof[n/1024] @65,664 | hist[B] @131,200
    int* S   = (int*)d_ws;
    int* gof = (int*)((char*)d_ws + 65664);
    unsigned long long* hist = (unsigned long long*)((char*)d_ws + 131200);

    hipMemsetAsync((char*)d_ws + 131200, 0, (size_t)B * 8, stream);

    const int nsamp = n / SSTR;                               // 65,536
    sample_bounds_kernel<<<(nsamp + 255) / 256, 256, 0, stream>>>(batch, S, gof, n, B);

    const int waves  = (n + 1023) / 1024;                     // 16,384
    const int blocks = (waves * 64 + 255) / 256;              // 4,096
    stream_kernel<<<blocks, 256, 0, stream>>>(ntype, S, gof, hist, n);

    mlp_kernel<<<(B + 255) / 256, 256, 0, stream>>>(hist, W1, b1, W2, b2, W3, b3, out, B);
}

// Round 9
// 37.342 us; speedup vs baseline: 1.2401x; 1.2401x over previous
//
#include <hip/hip_runtime.h>

// StructOnlyClassifier R9: pure-throughput decomposition (no long per-wave chains).
//  K1  bounds: S[g]=lower_bound(batch,g), windowed quad binary search (proven R7).
//  K1b invmap: thread per graph: hist[g]=0 and gof[w]=g for chunks w whose base
//      node 1024w lies in [S[g],S[g+1]) -- direct stores, no search.
//  K2  stream: one wave per FIXED 1024-node chunk. 4 independent dwordx4
//      loads/lane, per-quad packed counts, interval select via L2-hot S,
//      6-shfl u64 reduce, ~2 atomics/wave into hist. Copy-benchmark shape:
//      16384 short independent wave-jobs, 8 blocks/CU.
//  K3  mlp: thread per graph, LDS weights (proven R1).
// packed u64: [0:16)=cnt(t==0) [16:32)=cnt(t==1) [32:48)=cnt(t==2) [48:64)=total

__global__ __launch_bounds__(256) void bounds_kernel(
    const int* __restrict__ batch, int* __restrict__ S, int n, int B)
{
    const int g = blockIdx.x * 256 + threadIdx.x;
    if (g > B) return;
    const long long c = (long long)g * (long long)(n / B); // predicted S[g]
    long long Wn = 6144;                                    // 3 sigma
    int lo, hi;
    for (;;) {                       // deterministic bracket (widen on miss)
        long long l = c - Wn; if (l < 0) l = 0;
        long long h = c + Wn + 3; if (h > n) h = n;
        lo = (int)l & ~3;
        hi = (int)h & ~3;            // n is a multiple of 4
        const bool okL = (lo == 0) || (batch[lo - 1] < g);
        const bool okR = (hi == n) || (batch[hi] >= g);
        if (okL && okR) break;
        Wn <<= 2;                    // widens to [0,n] worst case
    }
    while (hi - lo > 4) {            // quad binary search, lo/hi stay 4-aligned
        const int mid = ((lo + hi) >> 1) & ~3;
        const int4 q = *(const int4*)(batch + mid);
        if (q.w < g)       lo = mid + 4;
        else if (q.x >= g) hi = mid;
        else { lo = mid; hi = mid + 4; }
    }
    int ans = lo;
    if (lo < hi) {
        const int4 q = *(const int4*)(batch + lo);
        ans = lo + (q.x < g) + (q.y < g) + (q.z < g) + (q.w < g);
    }
    S[g] = ans;
}

__global__ __launch_bounds__(256) void invmap_kernel(
    const int* __restrict__ S, int* __restrict__ gof,
    unsigned long long* __restrict__ hist, int B)
{
    const int g = blockIdx.x * 256 + threadIdx.x;
    if (g >= B) return;
    hist[g] = 0ull;
    const int s = S[g], e = S[g + 1];
    const int w0 = (s + 1023) >> 10;
    const int w1 = (e + 1023) >> 10;
    for (int w = w0; w < w1; ++w) gof[w] = g;   // avg 1 store per graph
}

__global__ __launch_bounds__(256) void stream_kernel(
    const int* __restrict__ ntype, const int* __restrict__ S,
    const int* __restrict__ gof, unsigned long long* __restrict__ hist, int n)
{
    const int tid  = threadIdx.x;
    const int w    = (blockIdx.x * 256 + tid) >> 6;    // one wave per 1024 nodes
    const int lane = tid & 63;
    const int ws   = w << 10;
    if (ws >= n) return;
    const int we = ws + 1024;                          // n is a multiple of 1024

    const int4* nt4 = (const int4*)ntype;
    const int q0 = (ws >> 2) + lane;
    int4 t[4];
    #pragma unroll
    for (int u = 0; u < 4; ++u) t[u] = nt4[q0 + u * 64]; // 4 independent 16B loads

    unsigned long long qp[4];                          // packed counts per quad
    #pragma unroll
    for (int u = 0; u < 4; ++u) {
        const int x = t[u].x, y = t[u].y, z = t[u].z, ww = t[u].w;
        const unsigned c0 = (x == 0) + (y == 0) + (z == 0) + (ww == 0);
        const unsigned c1 = (x == 1) + (y == 1) + (z == 1) + (ww == 1);
        const unsigned c2 = (x == 2) + (y == 2) + (z == 2) + (ww == 2);
        qp[u] = (unsigned long long)c0 | ((unsigned long long)c1 << 16)
              | ((unsigned long long)c2 << 32) | (4ull << 48);
    }

    int gcur = gof[w];                                 // graph containing node ws
    int lo = ws;
    for (;;) {
        const int b  = S[gcur + 1];                    // L2-hot (S is 64 KiB)
        const int hi = min(b, we);
        unsigned long long acc = 0;
        #pragma unroll
        for (int u = 0; u < 4; ++u) {
            const int qb = ws + u * 256 + lane * 4;
            if (qb >= lo && qb + 4 <= hi) {
                acc += qp[u];                          // quad fully inside interval
            } else if (qb < hi && qb + 4 > lo) {       // straddling quad (rare)
                const int e[4] = {t[u].x, t[u].y, t[u].z, t[u].w};
                #pragma unroll
                for (int c = 0; c < 4; ++c) {
                    const int idx = qb + c;
                    if (idx >= lo && idx < hi)
                        acc += (1ull << (e[c] * 16)) | (1ull << 48);
                }
            }
        }
        #pragma unroll
        for (int off = 32; off; off >>= 1) acc += __shfl_xor(acc, off);
        if (lane == 0 && acc) atomicAdd(&hist[gcur], acc);
        if (b >= we) break;
        ++gcur; lo = b;
    }
}

__global__ __launch_bounds__(256) void mlp_kernel(
    const unsigned long long* __restrict__ hist,
    const float* __restrict__ W1, const float* __restrict__ b1,
    const float* __restrict__ W2, const float* __restrict__ b2,
    const float* __restrict__ W3, const float* __restrict__ b3,
    float* __restrict__ out, int B)
{
    __shared__ float sW1[128], sb1[32], sW2[512], sb2[16], sW3[16], sb3[1];
    const int tid = threadIdx.x;
    for (int i = tid; i < 128; i += 256) sW1[i] = W1[i];
    for (int i = tid; i < 512; i += 256) sW2[i] = W2[i];
    if (tid < 32)  sb1[tid] = b1[tid];
    if (tid < 16)  sb2[tid] = b2[tid];
    if (tid >= 32 && tid < 48) sW3[tid - 32] = W3[tid - 32];
    if (tid == 0)  sb3[0] = b3[0];
    __syncthreads();

    const int g = blockIdx.x * blockDim.x + tid;
    if (g >= B) return;

    const unsigned long long h = hist[g];
    const float f0 = (float)(int)( h        & 0xFFFFull) - 54.5f;
    const float f1 = (float)(int)((h >> 16) & 0xFFFFull);
    const float f2 = (float)(int)((h >> 32) & 0xFFFFull);
    const float f3 = (float)(int)( h >> 48)              - 56.5f;

    float h1[32];
    #pragma unroll
    for (int j = 0; j < 32; ++j) {
        float s = sb1[j];
        s = fmaf(f0, sW1[      j], s);
        s = fmaf(f1, sW1[ 32 + j], s);
        s = fmaf(f2, sW1[ 64 + j], s);
        s = fmaf(f3, sW1[ 96 + j], s);
        h1[j] = fmaxf(0.0f, s);
    }
    float h2[16];
    #pragma unroll
    for (int m = 0; m < 16; ++m) {
        float s = sb2[m];
        #pragma unroll
        for (int j = 0; j < 32; ++j)
            s = fmaf(h1[j], sW2[j * 16 + m], s);
        h2[m] = fmaxf(0.0f, s);
    }
    float o = sb3[0];
    #pragma unroll
    for (int m = 0; m < 16; ++m)
        o = fmaf(h2[m], sW3[m], o);
    out[g] = o;
}

extern "C" void kernel_launch(void* const* d_in, const int* in_sizes, int n_in,
                              void* d_out, int out_size, void* d_ws, size_t ws_size,
                              hipStream_t stream) {
    // inputs: 0:x(N) 1:batch(N) 2:node_type(N) 3:num_graphs 4:W1 5:b1 6:W2 7:b2 8:W3 9:b3
    const int*   batch = (const int*)d_in[1];
    const int*   ntype = (const int*)d_in[2];
    const float* W1    = (const float*)d_in[4];
    const float* b1    = (const float*)d_in[5];
    const float* W2    = (const float*)d_in[6];
    const float* b2    = (const float*)d_in[7];
    const float* W3    = (const float*)d_in[8];
    const float* b3    = (const float*)d_in[9];
    float*       out   = (float*)d_out;

    const int n = in_sizes[1];          // 16,777,216 nodes
    const int B = out_size;             // 16,384 graphs

    // workspace: S[B+1] @0 | gof[n/1024] @65664 | hist[B] @131200 (8B aligned)
    int* S   = (int*)d_ws;
    int* gof = (int*)((char*)d_ws + 65664);
    unsigned long long* hist = (unsigned long long*)((char*)d_ws + 131200);

    bounds_kernel<<<(B + 1 + 255) / 256, 256, 0, stream>>>(batch, S, n, B);
    invmap_kernel<<<(B + 255) / 256, 256, 0, stream>>>(S, gof, hist, B);

    const int waves  = n >> 10;                      // 16,384 chunks
    const int blocks = waves / 4;                    // 4,096 blocks x 4 waves
    stream_kernel<<<blocks, 256, 0, stream>>>(ntype, S, gof, hist, n);

    mlp_kernel<<<(B + 255) / 256, 256, 0, stream>>>(hist, W1, b1, W2, b2, W3, b3, out, B);
}

// Round 10
// 36.455 us; speedup vs baseline: 1.2702x; 1.0243x over previous
//
#include <hip/hip_runtime.h>

// StructOnlyClassifier R10: overlap the boundary search with the stream.
//  K1 (two block roles, one kernel):
//    blocks [0,65):   S[g] = lower_bound(batch,g) via windowed quad binary
//                     search (proven R7/R9). Latency chains hide under...
//    blocks [65,..):  dependency-free ntype stream: one wave per 1024-node
//                     chunk, 4 independent dwordx4/lane; per 64-node sub-chunk
//                     emit packed u64 partial {c0 | c1<<32} (256K partials,
//                     2 MB, L2-resident). No S, no atomics, no interval logic.
//  K2: one wave per graph: sum interior sub-chunk partials (L2-hot), fix up
//      the two boundary sub-chunks by re-reading <=64 ntype nodes each
//      (L3-hot), wave-reduce, then the proven in-wave 4->32->16->1 MLP.

constexpr int BB = 65;   // bounds blocks (65*256 = 16640 >= B+1)

__global__ __launch_bounds__(256) void k1_bounds_stream(
    const int* __restrict__ batch, const int* __restrict__ ntype,
    int* __restrict__ S, unsigned long long* __restrict__ partial,
    int n, int B)
{
    const int bid = blockIdx.x;
    const int tid = threadIdx.x;

    if (bid < BB) {
        // ---- role A: boundary search ----
        const int g = bid * 256 + tid;
        if (g > B) return;
        const long long c = (long long)g * (long long)(n / B); // predicted S[g]
        long long Wn = 6144;                                    // 3 sigma
        int lo, hi;
        for (;;) {                       // deterministic bracket (widen on miss)
            long long l = c - Wn; if (l < 0) l = 0;
            long long h = c + Wn + 3; if (h > n) h = n;
            lo = (int)l & ~3;
            hi = (int)h & ~3;            // n is a multiple of 4
            const bool okL = (lo == 0) || (batch[lo - 1] < g);
            const bool okR = (hi == n) || (batch[hi] >= g);
            if (okL && okR) break;
            Wn <<= 2;
        }
        while (hi - lo > 4) {            // quad binary search, 4-aligned bounds
            const int mid = ((lo + hi) >> 1) & ~3;
            const int4 q = *(const int4*)(batch + mid);
            if (q.w < g)       lo = mid + 4;
            else if (q.x >= g) hi = mid;
            else { lo = mid; hi = mid + 4; }
        }
        int ans = lo;
        if (lo < hi) {
            const int4 q = *(const int4*)(batch + lo);
            ans = lo + (q.x < g) + (q.y < g) + (q.z < g) + (q.w < g);
        }
        S[g] = ans;
    } else {
        // ---- role B: dependency-free ntype stream -> sub-chunk partials ----
        const int w    = (bid - BB) * 4 + (tid >> 6);   // chunk id, [0, n/1024)
        const int lane = tid & 63;
        const int ws   = w << 10;
        if (ws >= n) return;

        const int4* nt4 = (const int4*)ntype;
        const int q0 = (ws >> 2) + lane;
        #pragma unroll
        for (int u = 0; u < 4; ++u) {                   // 4 independent 16B loads
            const int4 t = nt4[q0 + u * 64];
            const unsigned c0 = (t.x == 0) + (t.y == 0) + (t.z == 0) + (t.w == 0);
            const unsigned c1 = (t.x == 1) + (t.y == 1) + (t.z == 1) + (t.w == 1);
            unsigned long long p = (unsigned long long)c0
                                 | ((unsigned long long)c1 << 32);
            // reduce within each 16-lane group = one 64-node sub-chunk
            p += __shfl_xor(p, 1);
            p += __shfl_xor(p, 2);
            p += __shfl_xor(p, 4);
            p += __shfl_xor(p, 8);
            if ((lane & 15) == 0)
                partial[w * 16 + u * 4 + (lane >> 4)] = p;
        }
    }
}

__global__ __launch_bounds__(256) void k2_gather_mlp(
    const int* __restrict__ ntype, const int* __restrict__ S,
    const unsigned long long* __restrict__ partial,
    const float* __restrict__ W1, const float* __restrict__ b1,
    const float* __restrict__ W2, const float* __restrict__ b2,
    const float* __restrict__ W3, const float* __restrict__ b3,
    float* __restrict__ out, int B)
{
    __shared__ float sW1[128], sW2[512], sb1[32], sb2[16], sW3[16], sb3v[1];
    const int tid = threadIdx.x;
    if (tid < 128) sW1[tid] = W1[tid];
    sW2[tid]       = W2[tid];
    sW2[tid + 256] = W2[tid + 256];
    if      (tid < 32)  sb1[tid]      = b1[tid];
    else if (tid < 48)  sb2[tid - 32] = b2[tid - 32];
    else if (tid < 64)  sW3[tid - 48] = W3[tid - 48];
    else if (tid == 64) sb3v[0]       = b3[0];
    __syncthreads();

    const int lane = tid & 63;
    const int g    = (blockIdx.x * 256 + tid) >> 6;     // one wave per graph
    if (g >= B) return;

    const int s   = S[g];
    const int e   = S[g + 1];
    const int len = e - s;

    const int ca = (s + 63) & ~63;                      // ceil64(s)
    const int fb = e & ~63;                             // floor64(e)

    unsigned long long acc = 0;

    {   // left partial sub-chunk: nodes [s, min(e, ca))
        const int idx = (s & ~63) + lane;
        const int lim = min(e, ca);
        if (idx >= s && idx < lim) {
            const int v = ntype[idx];                   // L3-hot (just streamed)
            acc += (unsigned long long)(v == 0)
                 | ((unsigned long long)(v == 1) << 32);
        }
    }
    // interior full sub-chunks [ca/64, fb/64): L2-hot partial sums
    for (int i = (ca >> 6) + lane; i < (fb >> 6); i += 64)
        acc += partial[i];
    {   // right partial sub-chunk: nodes [fb, e), only when disjoint from left
        if (fb >= ca) {
            const int idx = fb + lane;
            if (idx < e) {
                const int v = ntype[idx];
                acc += (unsigned long long)(v == 0)
                     | ((unsigned long long)(v == 1) << 32);
            }
        }
    }

    #pragma unroll
    for (int off = 32; off; off >>= 1) acc += __shfl_xor(acc, off);
    const int c0t = (int)(acc & 0xFFFFFFFFull);
    const int c1t = (int)(acc >> 32);

    const float f0 = (float)c0t - 54.5f;
    const float f1 = (float)c1t;
    const float f2 = (float)(len - c0t - c1t);
    const float f3 = (float)len - 56.5f;

    // layer 1: unit j on lane&31 (lanes 32-63 duplicate harmlessly)
    const int j = lane & 31;
    float h1 = sb1[j];
    h1 = fmaf(f0, sW1[      j], h1);
    h1 = fmaf(f1, sW1[ 32 + j], h1);
    h1 = fmaf(f2, sW1[ 64 + j], h1);
    h1 = fmaf(f3, sW1[ 96 + j], h1);
    h1 = fmaxf(0.0f, h1);

    // layer 2: unit m on lane&15, h1 broadcast via shfl, W2 from LDS
    const int m = lane & 15;
    float s2 = sb2[m];
    #pragma unroll
    for (int jj = 0; jj < 32; ++jj)
        s2 = fmaf(__shfl(h1, jj), sW2[jj * 16 + m], s2);
    const float h2 = fmaxf(0.0f, s2);

    // layer 3: reduce 16 units within the 16-lane group
    float p3 = h2 * sW3[m];
    p3 += __shfl_xor(p3, 8);
    p3 += __shfl_xor(p3, 4);
    p3 += __shfl_xor(p3, 2);
    p3 += __shfl_xor(p3, 1);

    if (lane == 0) out[g] = p3 + sb3v[0];
}

extern "C" void kernel_launch(void* const* d_in, const int* in_sizes, int n_in,
                              void* d_out, int out_size, void* d_ws, size_t ws_size,
                              hipStream_t stream) {
    // inputs: 0:x(N) 1:batch(N) 2:node_type(N) 3:num_graphs 4:W1 5:b1 6:W2 7:b2 8:W3 9:b3
    const int*   batch = (const int*)d_in[1];
    const int*   ntype = (const int*)d_in[2];
    const float* W1    = (const float*)d_in[4];
    const float* b1    = (const float*)d_in[5];
    const float* W2    = (const float*)d_in[6];
    const float* b2    = (const float*)d_in[7];
    const float* W3    = (const float*)d_in[8];
    const float* b3    = (const float*)d_in[9];
    float*       out   = (float*)d_out;

    const int n = in_sizes[1];          // 16,777,216 nodes
    const int B = out_size;             // 16,384 graphs

    // workspace: S[B+1] @0 (65,540 B) | partial[n/64] @65,664 (2 MB)
    int* S = (int*)d_ws;
    unsigned long long* partial = (unsigned long long*)((char*)d_ws + 65664);

    const int stream_blocks = (n >> 10) / 4;             // 4096
    k1_bounds_stream<<<BB + stream_blocks, 256, 0, stream>>>(
        batch, ntype, S, partial, n, B);

    k2_gather_mlp<<<(B * 64 + 255) / 256, 256, 0, stream>>>(
        ntype, S, partial, W1, b1, W2, b2, W3, b3, out, B);
}

// Round 11
// 28.960 us; speedup vs baseline: 1.5990x; 1.2588x over previous
//
#include <hip/hip_runtime.h>

// StructOnlyClassifier R11: R6's single fused kernel (one wave per 4 graphs),
// with the 12-probe windowed binary search replaced by INTERPOLATION search
// (~3-4 probes; batch is uniform so S[g] is near-linear). Bracket maintained
// from actual probes -> unconditionally correct; binary fallback after 5
// interp steps guarantees termination. Everything else identical to R6.

constexpr int GPW = 4;   // graphs per wave

__device__ __forceinline__ int interp_lower_bound(
    const int* __restrict__ batch, int n, int stride, int g)
{
    // first idx with batch[idx] >= g.  Invariant: lb in [blo, bhi],
    // batch[blo-1] < g (or blo==0), batch[bhi] >= g (or bhi==n).
    // blo/bhi stay multiples of 4.
    int blo = 0, bhi = n;
    long long pos = (long long)g * stride - (stride >> 1);
    int it = 0;
    while (bhi - blo > 4) {
        int p;
        if (it < 5) {                         // interpolation phase
            long long pc = pos;
            if (pc < blo) pc = blo;
            if (pc > bhi - 4) pc = bhi - 4;
            p = (int)pc & ~3;                 // blo 4-aligned -> p >= blo
            ++it;
        } else {                              // binary fallback (guaranteed log)
            p = ((blo + bhi) >> 1) & ~3;
            if (p > bhi - 4) p = bhi - 4;
        }
        const int4 q = *(const int4*)(batch + p);
        if (q.w < g) {                        // lb > p+3
            blo = p + 4;
            pos = p + 4 + (long long)(g - q.w) * stride - (stride >> 1);
        } else if (q.x >= g) {                // lb <= p
            bhi = p;
            pos = p + (long long)(g - q.x) * stride - (stride >> 1);
        } else {                              // boundary inside this quad
            return p + 1 + (q.y < g) + (q.z < g);
        }
    }
    if (bhi > blo) {                          // bhi-blo == 4: count final quad
        const int4 q = *(const int4*)(batch + blo);
        return blo + (q.x < g) + (q.y < g) + (q.z < g) + (q.w < g);
    }
    return blo;
}

__global__ __launch_bounds__(256) void fused_kernel(
    const int* __restrict__ batch, const int* __restrict__ ntype,
    const float* __restrict__ W1, const float* __restrict__ b1,
    const float* __restrict__ W2, const float* __restrict__ b2,
    const float* __restrict__ W3, const float* __restrict__ b3,
    float* __restrict__ out, int n, int B, int stride)
{
    __shared__ float sW1[128], sW2[512], sb1[32], sb2[16], sW3[16], sb3v[1];
    const int tid = threadIdx.x;
    if (tid < 128) sW1[tid] = W1[tid];
    sW2[tid]       = W2[tid];
    sW2[tid + 256] = W2[tid + 256];
    if      (tid < 32)  sb1[tid]      = b1[tid];
    else if (tid < 48)  sb2[tid - 32] = b2[tid - 32];
    else if (tid < 64)  sW3[tid - 48] = W3[tid - 48];
    else if (tid == 64) sb3v[0]       = b3[0];
    __syncthreads();

    const int wid  = (blockIdx.x * 256 + tid) >> 6;
    const int lane = tid & 63;
    const int g0   = wid * GPW;
    if (g0 >= B) return;

    // ---- parallel boundary searches on lanes 0..GPW (~4 probes each) ----
    int ans = 0;
    if (lane <= GPW) {
        const int g = min(g0 + lane, B);
        ans = interp_lower_bound(batch, n, stride, g);
    }

    // ---- per-graph: coalesced segment count + MLP (identical to R6) ----
    for (int i = 0; i < GPW; ++i) {
        const int g = g0 + i;
        if (g >= B) break;
        const int s   = __shfl(ans, i);
        const int e   = __shfl(ans, i + 1);
        const int len = e - s;

        int c0 = 0, c1 = 0;
        int sa = (s + 3) & ~3; if (sa > e) sa = e;
        int ea = e & ~3;       if (ea < sa) ea = sa;

        {   // head scalars [s, sa)
            const int idx = s + lane;
            if (idx < sa) { const int v = ntype[idx]; c0 += (v == 0); c1 += (v == 1); }
        }
        {   // main int4 quads [sa, ea), lane-contiguous
            const int4* nt4 = (const int4*)ntype;
            for (int q = (sa >> 2) + lane; q < (ea >> 2); q += 64) {
                const int4 v = nt4[q];
                c0 += (v.x == 0) + (v.y == 0) + (v.z == 0) + (v.w == 0);
                c1 += (v.x == 1) + (v.y == 1) + (v.z == 1) + (v.w == 1);
            }
        }
        {   // tail scalars [ea, e)
            const int idx = ea + lane;
            if (idx < e) { const int v = ntype[idx]; c0 += (v == 0); c1 += (v == 1); }
        }

        unsigned long long p = (unsigned)c0 | ((unsigned long long)(unsigned)c1 << 32);
        #pragma unroll
        for (int off = 32; off; off >>= 1) p += __shfl_xor(p, off);
        const int c0t = (int)(p & 0xFFFFFFFFull);
        const int c1t = (int)(p >> 32);

        const float f0 = (float)c0t - 54.5f;
        const float f1 = (float)c1t;
        const float f2 = (float)(len - c0t - c1t);
        const float f3 = (float)len - 56.5f;

        // layer 1: unit j on lane&31 (lanes 32-63 duplicate harmlessly)
        const int j = lane & 31;
        float h1 = sb1[j];
        h1 = fmaf(f0, sW1[      j], h1);
        h1 = fmaf(f1, sW1[ 32 + j], h1);
        h1 = fmaf(f2, sW1[ 64 + j], h1);
        h1 = fmaf(f3, sW1[ 96 + j], h1);
        h1 = fmaxf(0.0f, h1);

        // layer 2: unit m on lane&15, h1 broadcast via shfl, W2 from LDS
        const int m = lane & 15;
        float s2 = sb2[m];
        #pragma unroll
        for (int jj = 0; jj < 32; ++jj)
            s2 = fmaf(__shfl(h1, jj), sW2[jj * 16 + m], s2);
        const float h2 = fmaxf(0.0f, s2);

        // layer 3: reduce 16 units within the 16-lane group
        float p3 = h2 * sW3[m];
        p3 += __shfl_xor(p3, 8);
        p3 += __shfl_xor(p3, 4);
        p3 += __shfl_xor(p3, 2);
        p3 += __shfl_xor(p3, 1);

        if (lane == 0) out[g] = p3 + sb3v[0];
    }
}

extern "C" void kernel_launch(void* const* d_in, const int* in_sizes, int n_in,
                              void* d_out, int out_size, void* d_ws, size_t ws_size,
                              hipStream_t stream) {
    // inputs: 0:x(N) 1:batch(N) 2:node_type(N) 3:num_graphs 4:W1 5:b1 6:W2 7:b2 8:W3 9:b3
    const int*   batch = (const int*)d_in[1];
    const int*   ntype = (const int*)d_in[2];
    const float* W1    = (const float*)d_in[4];
    const float* b1    = (const float*)d_in[5];
    const float* W2    = (const float*)d_in[6];
    const float* b2    = (const float*)d_in[7];
    const float* W3    = (const float*)d_in[8];
    const float* b3    = (const float*)d_in[9];
    float*       out   = (float*)d_out;

    const int n = in_sizes[1];          // 16,777,216 nodes
    const int B = out_size;             // 16,384 graphs

    const int waves  = (B + GPW - 1) / GPW;          // 4096
    const int blocks = (waves * 64 + 255) / 256;     // 1024
    fused_kernel<<<blocks, 256, 0, stream>>>(
        batch, ntype, W1, b1, W2, b2, W3, b3, out, n, B, n / B);
}

// Round 12
// 27.263 us; speedup vs baseline: 1.6985x; 1.0622x over previous
//
#include <hip/hip_runtime.h>

// StructOnlyClassifier R12: R11's fused kernel, max memory-level parallelism.
//  - GPW=2 -> 8192 waves = 32 waves/CU (full occupancy; R11 had 16/CU).
//  - Per graph: FIXED 5-deep unrolled clamped+masked dwordx4 loads (covers
//    1280 nodes = mean+8sigma; sigma=sqrt(1024)=32) + dynamic fallback loop
//    (normally zero-trip). Both graphs' 10 loads issue before any MLP.
//  - Dual-graph MLP: lanes 0-31 run graph A's layers, lanes 32-63 graph B's
//    -> layer-2 dependent chain halved vs sequential per-graph MLP.
//  - Boundaries: interpolation search (~4 probes) on lanes 0..2 (proven R11).

constexpr int GPW = 2;
constexpr int UNR = 5;     // 5*64 quads = 1280 nodes per graph before fallback

__device__ __forceinline__ int interp_lower_bound(
    const int* __restrict__ batch, int n, int stride, int g)
{
    // first idx with batch[idx] >= g. Invariant: lb in [blo, bhi], 4-aligned.
    int blo = 0, bhi = n;
    long long pos = (long long)g * stride - (stride >> 1);
    int it = 0;
    while (bhi - blo > 4) {
        int p;
        if (it < 5) {                         // interpolation phase
            long long pc = pos;
            if (pc < blo) pc = blo;
            if (pc > bhi - 4) pc = bhi - 4;
            p = (int)pc & ~3;
            ++it;
        } else {                              // binary fallback
            p = ((blo + bhi) >> 1) & ~3;
            if (p > bhi - 4) p = bhi - 4;
        }
        const int4 q = *(const int4*)(batch + p);
        if (q.w < g) {
            blo = p + 4;
            pos = p + 4 + (long long)(g - q.w) * stride - (stride >> 1);
        } else if (q.x >= g) {
            bhi = p;
            pos = p + (long long)(g - q.x) * stride - (stride >> 1);
        } else {
            return p + 1 + (q.y < g) + (q.z < g);
        }
    }
    if (bhi > blo) {
        const int4 q = *(const int4*)(batch + blo);
        return blo + (q.x < g) + (q.y < g) + (q.z < g) + (q.w < g);
    }
    return blo;
}

__global__ __launch_bounds__(256) void fused_kernel(
    const int* __restrict__ batch, const int* __restrict__ ntype,
    const float* __restrict__ W1, const float* __restrict__ b1,
    const float* __restrict__ W2, const float* __restrict__ b2,
    const float* __restrict__ W3, const float* __restrict__ b3,
    float* __restrict__ out, int n, int B, int stride)
{
    __shared__ float sW1[128], sW2[512], sb1[32], sb2[16], sW3[16], sb3v[1];
    const int tid = threadIdx.x;
    if (tid < 128) sW1[tid] = W1[tid];
    sW2[tid]       = W2[tid];
    sW2[tid + 256] = W2[tid + 256];
    if      (tid < 32)  sb1[tid]      = b1[tid];
    else if (tid < 48)  sb2[tid - 32] = b2[tid - 32];
    else if (tid < 64)  sW3[tid - 48] = W3[tid - 48];
    else if (tid == 64) sb3v[0]       = b3[0];
    __syncthreads();

    const int wid  = (blockIdx.x * 256 + tid) >> 6;
    const int lane = tid & 63;
    const int g0   = wid * GPW;
    if (g0 >= B) return;

    // ---- boundary searches on lanes 0..2 (~4 probes each, independent) ----
    int ans = 0;
    if (lane <= GPW) ans = interp_lower_bound(batch, n, stride, min(g0 + lane, B));
    const int s0 = __shfl(ans, 0);
    const int s1 = __shfl(ans, 1);
    const int s2b = __shfl(ans, 2);

    // ---- phase 1: stream counts for BOTH graphs (20 independent loads) ----
    const int4* nt4 = (const int4*)ntype;
    const int nqm1 = (n >> 2) - 1;
    int c0[2] = {0, 0}, c1[2] = {0, 0};

    #pragma unroll
    for (int i = 0; i < 2; ++i) {
        const int s = (i == 0) ? s0 : s1;
        const int e = (i == 0) ? s1 : s2b;
        int sa = (s + 3) & ~3; if (sa > e) sa = e;
        int ea = e & ~3;       if (ea < sa) ea = sa;

        {   // head scalars [s, sa): <=3 active lanes
            const int idx = s + lane;
            if (idx < sa) { const int v = ntype[idx]; c0[i] += (v == 0); c1[i] += (v == 1); }
        }
        const int qa = (sa >> 2) + lane;
        const int qe = (ea >> 2);
        #pragma unroll
        for (int u = 0; u < UNR; ++u) {       // fixed-depth independent loads
            const int qi = qa + u * 64;
            const int4 v = nt4[min(qi, nqm1)];
            if (qi < qe) {
                c0[i] += (v.x == 0) + (v.y == 0) + (v.z == 0) + (v.w == 0);
                c1[i] += (v.x == 1) + (v.y == 1) + (v.z == 1) + (v.w == 1);
            }
        }
        for (int qi = qa + UNR * 64; qi < qe; qi += 64) {  // pathological fallback
            const int4 v = nt4[qi];
            c0[i] += (v.x == 0) + (v.y == 0) + (v.z == 0) + (v.w == 0);
            c1[i] += (v.x == 1) + (v.y == 1) + (v.z == 1) + (v.w == 1);
        }
        {   // tail scalars [ea, e): <=3 active lanes
            const int idx = ea + lane;
            if (idx < e) { const int v = ntype[idx]; c0[i] += (v == 0); c1[i] += (v == 1); }
        }
    }

    // ---- dual wave-reduce (chains interleave) ----
    unsigned long long pa = (unsigned)c0[0] | ((unsigned long long)(unsigned)c1[0] << 32);
    unsigned long long pb = (unsigned)c0[1] | ((unsigned long long)(unsigned)c1[1] << 32);
    #pragma unroll
    for (int off = 32; off; off >>= 1) {
        pa += __shfl_xor(pa, off);
        pb += __shfl_xor(pb, off);
    }

    // ---- phase 2: both MLPs concurrently (graph = lane>=32 half) ----
    const bool hb = (lane >= 32);
    const int c0t = hb ? (int)(pb & 0xFFFFFFFFull) : (int)(pa & 0xFFFFFFFFull);
    const int c1t = hb ? (int)(pb >> 32)           : (int)(pa >> 32);
    const int len = hb ? (s2b - s1)                : (s1 - s0);

    const float f0 = (float)c0t - 54.5f;
    const float f1 = (float)c1t;
    const float f2 = (float)(len - c0t - c1t);
    const float f3 = (float)len - 56.5f;

    // layer 1: unit j on lane&31, per half
    const int j = lane & 31;
    float h1 = sb1[j];
    h1 = fmaf(f0, sW1[      j], h1);
    h1 = fmaf(f1, sW1[ 32 + j], h1);
    h1 = fmaf(f2, sW1[ 64 + j], h1);
    h1 = fmaf(f3, sW1[ 96 + j], h1);
    h1 = fmaxf(0.0f, h1);

    // layer 2: unit m on lane&15, h1 broadcast half-locally
    const int m = lane & 15;
    const int hbase = lane & 32;
    float sm = sb2[m];
    #pragma unroll
    for (int jj = 0; jj < 32; ++jj)
        sm = fmaf(__shfl(h1, hbase + jj), sW2[jj * 16 + m], sm);
    const float h2 = fmaxf(0.0f, sm);

    // layer 3: reduce 16 units within the 16-lane group
    float p3 = h2 * sW3[m];
    p3 += __shfl_xor(p3, 8);
    p3 += __shfl_xor(p3, 4);
    p3 += __shfl_xor(p3, 2);
    p3 += __shfl_xor(p3, 1);

    if (lane == 0)                          out[g0]     = p3 + sb3v[0];
    if (lane == 32 && g0 + 1 < B)           out[g0 + 1] = p3 + sb3v[0];
}

extern "C" void kernel_launch(void* const* d_in, const int* in_sizes, int n_in,
                              void* d_out, int out_size, void* d_ws, size_t ws_size,
                              hipStream_t stream) {
    // inputs: 0:x(N) 1:batch(N) 2:node_type(N) 3:num_graphs 4:W1 5:b1 6:W2 7:b2 8:W3 9:b3
    const int*   batch = (const int*)d_in[1];
    const int*   ntype = (const int*)d_in[2];
    const float* W1    = (const float*)d_in[4];
    const float* b1    = (const float*)d_in[5];
    const float* W2    = (const float*)d_in[6];
    const float* b2    = (const float*)d_in[7];
    const float* W3    = (const float*)d_in[8];
    const float* b3    = (const float*)d_in[9];
    float*       out   = (float*)d_out;

    const int n = in_sizes[1];          // 16,777,216 nodes
    const int B = out_size;             // 16,384 graphs

    const int waves  = (B + GPW - 1) / GPW;          // 8192
    const int blocks = (waves * 64 + 255) / 256;     // 2048
    fused_kernel<<<blocks, 256, 0, stream>>>(
        batch, ntype, W1, b1, W2, b2, W3, b3, out, n, B, n / B);
}